// Round 1
// baseline (234.398 us; speedup 1.0000x reference)
//
#include <hip/hip_runtime.h>

#define EPS 1e-5f
// B=64, D=2048, E=64, H1=512, H2=256

typedef __attribute__((ext_vector_type(8))) short short8;
typedef __attribute__((ext_vector_type(4))) float f32x4;

__device__ __forceinline__ float bf2f(unsigned short s) {
  unsigned u = ((unsigned)s) << 16;
  return __uint_as_float(u);
}
__device__ __forceinline__ unsigned short f2bf(float f) {
  unsigned u = __float_as_uint(f);
  u = u + 0x7FFFu + ((u >> 16) & 1u);  // round-to-nearest-even
  return (unsigned short)(u >> 16);
}

// ---------- prep: a1 = g1*rsqrt(v1+eps); t2 = g2*rsqrt(v2+eps); c2 = t2*(b2-m2)+beta2 ----------
__global__ void prep_vec(const float* __restrict__ g1, const float* __restrict__ v1,
                         const float* __restrict__ g2, const float* __restrict__ v2,
                         const float* __restrict__ b2, const float* __restrict__ m2,
                         const float* __restrict__ beta2,
                         float* __restrict__ a1, float* __restrict__ t2, float* __restrict__ c2) {
  int t = threadIdx.x;
  if (t < 512) a1[t] = g1[t] * rsqrtf(v1[t] + EPS);
  if (t < 256) {
    float tv = g2[t] * rsqrtf(v2[t] + EPS);
    t2[t] = tv;
    c2[t] = tv * (b2[t] - m2[t]) + beta2[t];
  }
}

// ---------- P partial GEMM (split-K over d): Ppart[c][b][h] = sum_{d in chunk c} rep[b,d]*W1[d,h] ----------
__global__ __launch_bounds__(256) void p_partial(const float* __restrict__ rep,
                                                 const float* __restrict__ W1,
                                                 float* __restrict__ Ppart) {
  int x = blockIdx.x, t = threadIdx.x;
  int h = (x & 7) * 64 + (t & 63);
  int b = ((x >> 3) & 15) * 4 + (t >> 6);   // wave-uniform b -> broadcast rep loads
  int c = x >> 7;                            // 16 d-chunks of 128
  const float* w = W1 + (size_t)(c * 128) * 512 + h;
  const float* rp = rep + b * 2048 + c * 128;
  float acc = 0.f;
  #pragma unroll 8
  for (int d = 0; d < 128; ++d) acc = fmaf(rp[d], w[(size_t)d * 512], acc);
  Ppart[c * 32768 + b * 512 + h] = acc;
}

// ---------- P finalize: P[b,h] = bf16( a1[h]*(sum_c Ppart + b1[h] - m1[h]) + beta1[h] ) ----------
__global__ __launch_bounds__(256) void p_final(const float* __restrict__ Ppart,
                                               const float* __restrict__ a1,
                                               const float* __restrict__ b1,
                                               const float* __restrict__ m1,
                                               const float* __restrict__ beta1,
                                               unsigned short* __restrict__ P) {
  int idx = blockIdx.x * 256 + threadIdx.x;
  int h = idx & 511;
  float tot = 0.f;
  #pragma unroll
  for (int c = 0; c < 16; ++c) tot += Ppart[c * 32768 + idx];
  P[idx] = f2bf(a1[h] * (tot + b1[h] - m1[h]) + beta1[h]);
}

// ---------- Q[k,h] = bf16(a1[h]*(emb@W1e)[k,h]);  R[k,h] = bf16(a1[h]*W1[k,h]) ----------
__global__ __launch_bounds__(256) void qr_kernel(const float* __restrict__ emb,
                                                 const float* __restrict__ W1,
                                                 const float* __restrict__ a1,
                                                 unsigned short* __restrict__ Q,
                                                 unsigned short* __restrict__ R) {
  int x = blockIdx.x, t = threadIdx.x;
  int h = (x & 7) * 64 + (t & 63);
  int k = (x >> 3) * 4 + (t >> 6);          // wave-uniform k -> broadcast emb loads
  const float* We = W1 + 2048 * 512;
  float acc = 0.f;
  #pragma unroll 8
  for (int e = 0; e < 64; ++e) acc = fmaf(emb[k * 64 + e], We[e * 512 + h], acc);
  float a1h = a1[h];
  Q[k * 512 + h] = f2bf(a1h * acc);
  R[k * 512 + h] = f2bf(a1h * W1[(size_t)k * 512 + h]);
}

// ---------- W2t[o,h] = bf16(W2[h,o]) ----------
__global__ __launch_bounds__(256) void w2t_kernel(const float* __restrict__ W2,
                                                  unsigned short* __restrict__ W2t) {
  int h = blockIdx.x, o = threadIdx.x;
  W2t[o * 512 + h] = f2bf(W2[h * 256 + o]);
}

// ---------- fused main: per block, 2 k-values x all 64 b (rows r = 64*(k-k0)+b) ----------
// A[r,h] = relu(P[b,h] + Q[k,h] - rep[b,k]*R[k,h]) generated into LDS per 64-wide K chunk,
// C = A(128x512) @ W2(512x256) via mfma_f32_16x16x32_bf16, epilogue: relu(t2*c+c2)*w3 row-sum.
__global__ __launch_bounds__(256, 2) void fused_main(
    const float* __restrict__ rep,
    const unsigned short* __restrict__ P,
    const unsigned short* __restrict__ Q,
    const unsigned short* __restrict__ R,
    const unsigned short* __restrict__ W2t,
    const float* __restrict__ t2,
    const float* __restrict__ c2,
    const float* __restrict__ W3,
    const float* __restrict__ b3,
    float* __restrict__ out) {
  __shared__ unsigned short A_lds[128 * 72];   // 128 rows x 64 bf16, stride 72 (pad)
  __shared__ unsigned short W2_lds[256 * 72];  // 256 o-rows x 64 bf16, stride 72
  __shared__ float repc[128];
  __shared__ float partial[2][128];

  const int t = threadIdx.x;
  const int w = t >> 6;          // wave 0..3
  const int l = t & 63;
  const int k0 = blockIdx.x * 2;

  if (t < 128) repc[t] = rep[(t & 63) * 2048 + k0 + (t >> 6)];

  f32x4 acc[4][8];
  #pragma unroll
  for (int mi = 0; mi < 4; ++mi)
    #pragma unroll
    for (int nj = 0; nj < 8; ++nj)
      acc[mi][nj] = (f32x4){0.f, 0.f, 0.f, 0.f};

  const int wm = w >> 1, wn = w & 1;  // wave tile: M 64 x N 128
  const int lq = l >> 4;              // quad
  const int ln = l & 15;

  __syncthreads();

  for (int c = 0; c < 8; ++c) {
    const int h0 = c * 64;
    // ---- A generation: wave w covers rows [w*32, w*32+32), 2 rows/pass x 32 lanes x 2 h ----
    {
      const int hl = (l & 31) * 2;
      const int rhalf = l >> 5;
      #pragma unroll
      for (int p = 0; p < 16; ++p) {
        int r = w * 32 + p * 2 + rhalf;
        int b = r & 63;
        int kk = k0 + (r >> 6);
        unsigned pv = *(const unsigned*)(P + b * 512 + h0 + hl);
        unsigned qv = *(const unsigned*)(Q + kk * 512 + h0 + hl);
        unsigned rv = *(const unsigned*)(R + kk * 512 + h0 + hl);
        float rb = repc[r];
        float z0 = bf2f((unsigned short)(pv & 0xffffu)) + bf2f((unsigned short)(qv & 0xffffu))
                   - rb * bf2f((unsigned short)(rv & 0xffffu));
        float z1 = bf2f((unsigned short)(pv >> 16)) + bf2f((unsigned short)(qv >> 16))
                   - rb * bf2f((unsigned short)(rv >> 16));
        z0 = fmaxf(z0, 0.f);
        z1 = fmaxf(z1, 0.f);
        unsigned packed = (unsigned)f2bf(z0) | ((unsigned)f2bf(z1) << 16);
        *(unsigned*)(&A_lds[r * 72 + hl]) = packed;
      }
    }
    // ---- W2 chunk staging: 256 o-rows x 64 bf16; 8 lanes cover one 128B row-chunk ----
    {
      const int orow = t >> 3;
      const int seg = (t & 7) * 8;
      #pragma unroll
      for (int p = 0; p < 8; ++p) {
        int o = p * 32 + orow;
        uint4 v = *(const uint4*)(W2t + o * 512 + h0 + seg);
        *(uint4*)(&W2_lds[o * 72 + seg]) = v;
      }
    }
    __syncthreads();
    // ---- MFMA: 2 k-steps of 32 per chunk ----
    #pragma unroll
    for (int ks = 0; ks < 2; ++ks) {
      short8 afr[4], bfr[8];
      #pragma unroll
      for (int mi = 0; mi < 4; ++mi)
        afr[mi] = *(const short8*)(&A_lds[(wm * 64 + mi * 16 + ln) * 72 + ks * 32 + lq * 8]);
      #pragma unroll
      for (int nj = 0; nj < 8; ++nj)
        bfr[nj] = *(const short8*)(&W2_lds[(wn * 128 + nj * 16 + ln) * 72 + ks * 32 + lq * 8]);
      #pragma unroll
      for (int mi = 0; mi < 4; ++mi)
        #pragma unroll
        for (int nj = 0; nj < 8; ++nj)
          acc[mi][nj] = __builtin_amdgcn_mfma_f32_16x16x32_bf16(afr[mi], bfr[nj], acc[mi][nj], 0, 0, 0);
    }
    __syncthreads();
  }

  // ---- epilogue: u = t2[o]*acc + c2[o]; p = relu(u)*w3[o]; row-sum over o ----
  float t2v[8], c2v[8], w3v[8];
  #pragma unroll
  for (int nj = 0; nj < 8; ++nj) {
    int o = wn * 128 + nj * 16 + ln;
    t2v[nj] = t2[o];
    c2v[nj] = c2[o];
    w3v[nj] = W3[o];
  }
  #pragma unroll
  for (int mi = 0; mi < 4; ++mi) {
    float s[4] = {0.f, 0.f, 0.f, 0.f};
    #pragma unroll
    for (int nj = 0; nj < 8; ++nj)
      #pragma unroll
      for (int r = 0; r < 4; ++r) {
        float u = fmaf(t2v[nj], acc[mi][nj][r], c2v[nj]);
        u = fmaxf(u, 0.f);
        s[r] = fmaf(u, w3v[nj], s[r]);
      }
    #pragma unroll
    for (int r = 0; r < 4; ++r) {
      #pragma unroll
      for (int m = 1; m < 16; m <<= 1) s[r] += __shfl_xor(s[r], m, 64);
    }
    if (ln == 0) {
      int rowb = wm * 64 + mi * 16 + lq * 4;
      #pragma unroll
      for (int r = 0; r < 4; ++r) partial[wn][rowb + r] = s[r];
    }
  }
  __syncthreads();
  if (t < 128) {
    int b = t & 63;
    int kk = k0 + (t >> 6);
    out[b * 2048 + kk] = partial[0][t] + partial[1][t] + b3[0];
  }
}

extern "C" void kernel_launch(void* const* d_in, const int* in_sizes, int n_in,
                              void* d_out, int out_size, void* d_ws, size_t ws_size,
                              hipStream_t stream) {
  const float* rep   = (const float*)d_in[0];
  const float* emb   = (const float*)d_in[1];
  const float* W1    = (const float*)d_in[2];
  const float* b1    = (const float*)d_in[3];
  const float* g1    = (const float*)d_in[4];
  const float* beta1 = (const float*)d_in[5];
  const float* m1    = (const float*)d_in[6];
  const float* v1    = (const float*)d_in[7];
  const float* W2    = (const float*)d_in[8];
  const float* b2    = (const float*)d_in[9];
  const float* g2    = (const float*)d_in[10];
  const float* beta2 = (const float*)d_in[11];
  const float* m2    = (const float*)d_in[12];
  const float* v2    = (const float*)d_in[13];
  const float* W3    = (const float*)d_in[14];
  const float* b3    = (const float*)d_in[15];
  float* out = (float*)d_out;

  char* ws = (char*)d_ws;
  float* a1            = (float*)(ws + 0);            // 512 f32
  float* t2            = (float*)(ws + 2048);         // 256 f32
  float* c2            = (float*)(ws + 3072);         // 256 f32
  unsigned short* P    = (unsigned short*)(ws + 4096);     // 64x512 bf16
  unsigned short* Q    = (unsigned short*)(ws + 69632);    // 2048x512 bf16
  unsigned short* R    = (unsigned short*)(ws + 2166784);  // 2048x512 bf16
  unsigned short* W2t  = (unsigned short*)(ws + 4263936);  // 256x512 bf16
  float* Ppart         = (float*)(ws + 4526080);           // 16x64x512 f32

  prep_vec<<<1, 512, 0, stream>>>(g1, v1, g2, v2, b2, m2, beta2, a1, t2, c2);
  p_partial<<<2048, 256, 0, stream>>>(rep, W1, Ppart);
  p_final<<<128, 256, 0, stream>>>(Ppart, a1, b1, m1, beta1, P);
  qr_kernel<<<4096, 256, 0, stream>>>(emb, W1, a1, Q, R);
  w2t_kernel<<<512, 256, 0, stream>>>(W2, W2t);
  fused_main<<<1024, 256, 0, stream>>>(rep, P, Q, R, W2t, t2, c2, W3, b3, out);
}

// Round 2
// 194.505 us; speedup vs baseline: 1.2051x; 1.2051x over previous
//
#include <hip/hip_runtime.h>

#define EPS 1e-5f
// B=64, D=2048, E=64, H1=512, H2=256

typedef __attribute__((ext_vector_type(8))) short short8;
typedef __attribute__((ext_vector_type(4))) float f32x4;

__device__ __forceinline__ float bflo(unsigned u) { return __uint_as_float(u << 16); }
__device__ __forceinline__ float bfhi(unsigned u) { return __uint_as_float(u & 0xffff0000u); }
__device__ __forceinline__ unsigned short f2bf(float f) {
  unsigned u = __float_as_uint(f);
  u = u + 0x7FFFu + ((u >> 16) & 1u);  // RNE
  return (unsigned short)(u >> 16);
}
__device__ __forceinline__ unsigned pack2(float a, float b) {
  return (unsigned)f2bf(a) | ((unsigned)f2bf(b) << 16);
}

// ---------------- prep: Q,R (bf16), W2t (bf16 transpose), BN vectors ----------------
// blocks 0..255   : Q/R for 8 k-values each
// blocks 256..319 : W2t[o][h] = bf16(W2[h][o]), 8 h-cols per block
// block  320      : t2, c2, pbias
__global__ __launch_bounds__(256) void prep(
    const float* __restrict__ emb, const float* __restrict__ W1,
    const float* __restrict__ g1, const float* __restrict__ v1,
    const float* __restrict__ b1, const float* __restrict__ m1,
    const float* __restrict__ beta1,
    const float* __restrict__ W2,
    const float* __restrict__ g2, const float* __restrict__ v2,
    const float* __restrict__ b2, const float* __restrict__ m2,
    const float* __restrict__ beta2,
    unsigned* __restrict__ Q, unsigned* __restrict__ R,
    unsigned short* __restrict__ W2t,
    float* __restrict__ t2, float* __restrict__ c2, float* __restrict__ pbias) {
  const int x = blockIdx.x, t = threadIdx.x;
  if (x < 256) {
    const int k0 = x * 8;
    const int h = t * 2;
    const float a0 = g1[h] * rsqrtf(v1[h] + EPS);
    const float a1 = g1[h + 1] * rsqrtf(v1[h + 1] + EPS);
    const float* We = W1 + 2048 * 512;
    float acc0[8], acc1[8];
    #pragma unroll
    for (int k = 0; k < 8; ++k) { acc0[k] = 0.f; acc1[k] = 0.f; }
    for (int e = 0; e < 64; ++e) {
      float2 wv = *(const float2*)(We + e * 512 + h);
      #pragma unroll
      for (int k = 0; k < 8; ++k) {
        float ev = emb[(k0 + k) * 64 + e];  // wave-uniform -> s_load
        acc0[k] = fmaf(ev, wv.x, acc0[k]);
        acc1[k] = fmaf(ev, wv.y, acc1[k]);
      }
    }
    #pragma unroll
    for (int k = 0; k < 8; ++k) {
      Q[(k0 + k) * 256 + t] = pack2(a0 * acc0[k], a1 * acc1[k]);
      float2 wv = *(const float2*)(W1 + (size_t)(k0 + k) * 512 + h);
      R[(k0 + k) * 256 + t] = pack2(a0 * wv.x, a1 * wv.y);
    }
  } else if (x < 320) {
    const int h0 = (x - 256) * 8;
    const int o = t;
    unsigned d[4];
    #pragma unroll
    for (int i = 0; i < 4; ++i) {
      float v0 = W2[(h0 + 2 * i) * 256 + o];      // coalesced across o
      float v1_ = W2[(h0 + 2 * i + 1) * 256 + o];
      d[i] = pack2(v0, v1_);
    }
    *(uint4*)(W2t + o * 512 + h0) = make_uint4(d[0], d[1], d[2], d[3]);  // 16B/thread
  } else {
    float tv = g2[t] * rsqrtf(v2[t] + EPS);
    t2[t] = tv;
    c2[t] = tv * (b2[t] - m2[t]) + beta2[t];
    #pragma unroll
    for (int i = 0; i < 2; ++i) {
      int h = t + i * 256;
      float a = g1[h] * rsqrtf(v1[h] + EPS);
      pbias[h] = a * (b1[h] - m1[h]) + beta1[h];
    }
  }
}

// ---------------- P = bf16( rep @ R + pbias )  (since rep@(a1*W1d) = a1*(rep@W1d)) ----------------
// grid 64 (one block per b), 1024 threads = 16 k-slices x 64 h-octet lanes, LDS reduce.
__global__ __launch_bounds__(1024) void p_gemm(
    const float* __restrict__ rep, const unsigned* __restrict__ R,
    const float* __restrict__ pbias, unsigned* __restrict__ P) {
  __shared__ float red[16 * 512];
  const int b = blockIdx.x, t = threadIdx.x;
  const int lane = t & 63, kq = t >> 6;  // kq wave-uniform
  const int hl = lane * 8;
  const float* rp = rep + b * 2048 + kq * 128;
  const unsigned* Rp = R + (size_t)(kq * 128) * 256 + lane * 4;
  float acc[8];
  #pragma unroll
  for (int i = 0; i < 8; ++i) acc[i] = 0.f;
  #pragma unroll 4
  for (int k = 0; k < 128; ++k) {
    uint4 rv = *(const uint4*)(Rp + (size_t)k * 256);
    float rk = rp[k];  // wave-uniform scalar
    acc[0] = fmaf(rk, bflo(rv.x), acc[0]); acc[1] = fmaf(rk, bfhi(rv.x), acc[1]);
    acc[2] = fmaf(rk, bflo(rv.y), acc[2]); acc[3] = fmaf(rk, bfhi(rv.y), acc[3]);
    acc[4] = fmaf(rk, bflo(rv.z), acc[4]); acc[5] = fmaf(rk, bfhi(rv.z), acc[5]);
    acc[6] = fmaf(rk, bflo(rv.w), acc[6]); acc[7] = fmaf(rk, bfhi(rv.w), acc[7]);
  }
  *(f32x4*)(&red[kq * 512 + hl])     = (f32x4){acc[0], acc[1], acc[2], acc[3]};
  *(f32x4*)(&red[kq * 512 + hl + 4]) = (f32x4){acc[4], acc[5], acc[6], acc[7]};
  __syncthreads();
  if (t < 256) {
    const int h = t * 2;
    float s0 = 0.f, s1 = 0.f;
    #pragma unroll
    for (int q = 0; q < 16; ++q) { s0 += red[q * 512 + h]; s1 += red[q * 512 + h + 1]; }
    P[b * 256 + t] = pack2(s0 + pbias[h], s1 + pbias[h + 1]);
  }
}

// ---------------- fused main ----------------
// Block: 2 k-values x 64 b = 128 rows, N=256 (all o), K=512 in 8 chunks of 64.
// A generated into LDS in MFMA-fragment order (16B per (mi,ks,lq,ln) group):
// both ds_write_b128 and ds_read_b128 are lane-contiguous 1KB -> conflict-free.
// A double-buffered (one barrier per chunk); B-frags loaded straight from L2-resident W2t.
// Wave-tile: M=128 x N=64 (wave w owns o in [w*64, w*64+64)).
__global__ __launch_bounds__(256, 2) void fused_main(
    const float* __restrict__ rep,
    const unsigned* __restrict__ P,
    const unsigned* __restrict__ Q,
    const unsigned* __restrict__ Rm,
    const unsigned short* __restrict__ W2t,
    const float* __restrict__ t2, const float* __restrict__ c2,
    const float* __restrict__ W3, const float* __restrict__ b3,
    float* __restrict__ out) {
  __shared__ unsigned short A_lds[2][8192];  // 2 x 16KB, fragment-ordered
  __shared__ float repc[128];
  __shared__ float partial[4][128];

  const int t = threadIdx.x;
  const int w = t >> 6;
  const int ln = t & 15;
  const int lq = (t >> 4) & 3;
  const int ks_id = w & 1;   // gen role: which 32-wide half
  const int hi_id = w >> 1;  // gen role: mi parity
  const int k0 = blockIdx.x * 2;

  if (t < 128) repc[t] = rep[(t & 63) * 2048 + k0 + (t >> 6)];

  f32x4 acc[8][4];
  #pragma unroll
  for (int mi = 0; mi < 8; ++mi)
    #pragma unroll
    for (int nj = 0; nj < 4; ++nj) acc[mi][nj] = (f32x4){0.f, 0.f, 0.f, 0.f};

  __syncthreads();  // repc visible

  // generate chunk c of A (128 rows x 64 cols) into buf, fragment-ordered
  auto gen = [&](int c, unsigned short* buf) {
    const int colbase = c * 64 + ks_id * 32 + lq * 8;
    const int cb2 = colbase >> 1;
    #pragma unroll
    for (int p = 0; p < 4; ++p) {
      const int mi = p * 2 + hi_id;
      const int r = mi * 16 + ln;
      const int bb = r & 63;
      const int kg = k0 + (r >> 6);
      uint4 pv = *(const uint4*)(P + (bb << 8) + cb2);
      uint4 qv = *(const uint4*)(Q + (kg << 8) + cb2);
      uint4 rv = *(const uint4*)(Rm + (kg << 8) + cb2);
      const float rb = repc[r];
      unsigned d[4];
      {
        float z0 = fmaf(-rb, bflo(rv.x), bflo(pv.x) + bflo(qv.x));
        float z1 = fmaf(-rb, bfhi(rv.x), bfhi(pv.x) + bfhi(qv.x));
        d[0] = pack2(fmaxf(z0, 0.f), fmaxf(z1, 0.f));
        z0 = fmaf(-rb, bflo(rv.y), bflo(pv.y) + bflo(qv.y));
        z1 = fmaf(-rb, bfhi(rv.y), bfhi(pv.y) + bfhi(qv.y));
        d[1] = pack2(fmaxf(z0, 0.f), fmaxf(z1, 0.f));
        z0 = fmaf(-rb, bflo(rv.z), bflo(pv.z) + bflo(qv.z));
        z1 = fmaf(-rb, bfhi(rv.z), bfhi(pv.z) + bfhi(qv.z));
        d[2] = pack2(fmaxf(z0, 0.f), fmaxf(z1, 0.f));
        z0 = fmaf(-rb, bflo(rv.w), bflo(pv.w) + bflo(qv.w));
        z1 = fmaf(-rb, bfhi(rv.w), bfhi(pv.w) + bfhi(qv.w));
        d[3] = pack2(fmaxf(z0, 0.f), fmaxf(z1, 0.f));
      }
      *(uint4*)(&buf[(size_t)(p * 256 + t) * 8]) = make_uint4(d[0], d[1], d[2], d[3]);
    }
  };

  gen(0, A_lds[0]);

  for (int c = 0; c < 8; ++c) {
    __syncthreads();  // writes of buf[c&1] visible; prior reads of buf[(c+1)&1] done
    if (c < 7) gen(c + 1, A_lds[(c + 1) & 1]);
    const unsigned short* buf = A_lds[c & 1];
    #pragma unroll
    for (int ks = 0; ks < 2; ++ks) {
      short8 afr[8];
      #pragma unroll
      for (int mi = 0; mi < 8; ++mi)
        afr[mi] = *(const short8*)(buf + (size_t)((((mi * 2 + ks) * 4 + lq) * 16 + ln) * 8));
      short8 bfr[4];
      #pragma unroll
      for (int nj = 0; nj < 4; ++nj)
        bfr[nj] = *(const short8*)(W2t + (size_t)(w * 64 + nj * 16 + ln) * 512 + c * 64 + ks * 32 + lq * 8);
      #pragma unroll
      for (int mi = 0; mi < 8; ++mi)
        #pragma unroll
        for (int nj = 0; nj < 4; ++nj)
          acc[mi][nj] = __builtin_amdgcn_mfma_f32_16x16x32_bf16(afr[mi], bfr[nj], acc[mi][nj], 0, 0, 0);
    }
  }

  // epilogue: u = relu(t2[o]*acc + c2[o]) * W3[o]; reduce over o
  float t2v[4], c2v[4], w3v[4];
  #pragma unroll
  for (int nj = 0; nj < 4; ++nj) {
    int o = w * 64 + nj * 16 + ln;
    t2v[nj] = t2[o];
    c2v[nj] = c2[o];
    w3v[nj] = W3[o];
  }
  #pragma unroll
  for (int mi = 0; mi < 8; ++mi) {
    float s[4] = {0.f, 0.f, 0.f, 0.f};
    #pragma unroll
    for (int nj = 0; nj < 4; ++nj)
      #pragma unroll
      for (int r = 0; r < 4; ++r) {
        float u = fmaf(t2v[nj], acc[mi][nj][r], c2v[nj]);
        u = fmaxf(u, 0.f);
        s[r] = fmaf(u, w3v[nj], s[r]);
      }
    #pragma unroll
    for (int r = 0; r < 4; ++r) {
      #pragma unroll
      for (int m = 1; m < 16; m <<= 1) s[r] += __shfl_xor(s[r], m, 64);
    }
    if (ln == 0) {
      #pragma unroll
      for (int r = 0; r < 4; ++r) partial[w][mi * 16 + lq * 4 + r] = s[r];
    }
  }
  __syncthreads();
  if (t < 128) {
    out[(t & 63) * 2048 + k0 + (t >> 6)] =
        partial[0][t] + partial[1][t] + partial[2][t] + partial[3][t] + b3[0];
  }
}

extern "C" void kernel_launch(void* const* d_in, const int* in_sizes, int n_in,
                              void* d_out, int out_size, void* d_ws, size_t ws_size,
                              hipStream_t stream) {
  const float* rep   = (const float*)d_in[0];
  const float* emb   = (const float*)d_in[1];
  const float* W1    = (const float*)d_in[2];
  const float* b1    = (const float*)d_in[3];
  const float* g1    = (const float*)d_in[4];
  const float* beta1 = (const float*)d_in[5];
  const float* m1    = (const float*)d_in[6];
  const float* v1    = (const float*)d_in[7];
  const float* W2    = (const float*)d_in[8];
  const float* b2    = (const float*)d_in[9];
  const float* g2    = (const float*)d_in[10];
  const float* beta2 = (const float*)d_in[11];
  const float* m2    = (const float*)d_in[12];
  const float* v2    = (const float*)d_in[13];
  const float* W3    = (const float*)d_in[14];
  const float* b3    = (const float*)d_in[15];
  float* out = (float*)d_out;

  char* ws = (char*)d_ws;
  float* t2            = (float*)(ws + 0);        // 256 f32
  float* c2            = (float*)(ws + 1024);     // 256 f32
  float* pbias         = (float*)(ws + 2048);     // 512 f32
  unsigned* P          = (unsigned*)(ws + 4096);     // 64x512 bf16 (pairs)
  unsigned* Q          = (unsigned*)(ws + 69632);    // 2048x512 bf16 (pairs)
  unsigned* R          = (unsigned*)(ws + 2166784);  // 2048x512 bf16 (pairs)
  unsigned short* W2t  = (unsigned short*)(ws + 4263936);  // 256x512 bf16

  prep<<<321, 256, 0, stream>>>(emb, W1, g1, v1, b1, m1, beta1, W2, g2, v2, b2, m2,
                                beta2, Q, R, W2t, t2, c2, pbias);
  p_gemm<<<64, 1024, 0, stream>>>(rep, R, pbias, P);
  fused_main<<<1024, 256, 0, stream>>>(rep, P, Q, R, W2t, t2, c2, W3, b3, out);
}